// Round 9
// baseline (759.001 us; speedup 1.0000x reference)
//
#include <hip/hip_runtime.h>
#include <cstdint>
#include <cstddef>

#define NN 8192
#define ATOMF 64
#define HID 128
#define HEADS 8
#define NG 256
#define ELLW 192
#define NEGSLOPE 0.2f

typedef unsigned long long u64;

// ================= K1: adj -> ELL (lean, wave-per-row, LDS bitmask) ====
// row = (blockIdx.x % 2048)*4 + wid so the same kernel serves the x3 diagnostic grid.
__global__ __launch_bounds__(256, 4) void k_scan_ell(const float* __restrict__ adj,
                                                     int* __restrict__ ell,
                                                     int* __restrict__ deg) {
    __shared__ u64 bml[4][128];
    int t = threadIdx.x, wid = t >> 6, l = t & 63;
    int row = (blockIdx.x & 2047) * 4 + wid;
    const float4* a4 = (const float4*)(adj + (size_t)row * NN);
    u64* bmr = bml[wid];
    #pragma unroll 8
    for (int s = 0; s < 32; ++s) {
        float4 v = a4[s * 64 + l];                  // coalesced 1 KB per wave-instr
        u64 b0 = __ballot(v.x > 0.f);
        u64 b1 = __ballot(v.y > 0.f);
        u64 b2 = __ballot(v.z > 0.f);
        u64 b3 = __ballot(v.w > 0.f);
        if (l < 4) bmr[s * 4 + l] = (l == 0) ? b0 : (l == 1) ? b1 : (l == 2) ? b2 : b3;
    }
    __syncthreads();
    // ---- expand from LDS (R7-proven encoding/order) ----
    u64 w0 = bmr[2 * l];
    u64 w1 = bmr[2 * l + 1];
    int c = __popcll(w0) + __popcll(w1);
    int incl = c;
    #pragma unroll
    for (int o = 1; o < 64; o <<= 1) {
        int u = __shfl_up(incl, o);
        if (l >= o) incl += u;
    }
    int pos = incl - c;
    int total = __shfl(incl, 63);
    if (l == 0) deg[row] = total < ELLW ? total : ELLW;
    int* er = ell + (size_t)row * ELLW;
    int gw0 = 2 * l, gw1 = 2 * l + 1;
    int base0 = (gw0 >> 2) * 256 + (gw0 & 3);
    int base1 = (gw1 >> 2) * 256 + (gw1 & 3);
    while (w0) {
        int bit = __builtin_ctzll(w0);
        w0 &= w0 - 1;
        if (pos < ELLW) er[pos++] = base0 + 4 * bit;
    }
    while (w1) {
        int bit = __builtin_ctzll(w1);
        w1 &= w1 - 1;
        if (pos < ELLW) er[pos++] = base1 + 4 * bit;
    }
}

// ================= K2: wreduce + gemm0/scores0 (R8 verbatim) ====
__global__ __launch_bounds__(256) void k_front2(
    const float* __restrict__ x,
    const float* __restrict__ W0, const float* __restrict__ a0s, const float* __restrict__ a0d,
    const float* __restrict__ W1, const float* __restrict__ W2,
    float* __restrict__ Wr1, float* __restrict__ Wr2,
    float* __restrict__ g0, float* __restrict__ ssrc, float* __restrict__ sdst) {
    int b = blockIdx.x, t = threadIdx.x;
    if (b < 128) {
        const float* W = (b < 64) ? W1 : W2;
        float* Wr = (b < 64) ? Wr1 : Wr2;
        int i = (b & 63) * 256 + t;
        int k = i >> 7, cc = i & 127;
        float s = 0.f;
        #pragma unroll
        for (int h = 0; h < HEADS; ++h) s += W[(size_t)(h * HID + k) * HID + cc];
        Wr[i] = s;
    } else {
        __shared__ float Xl[32 * ATOMF];
        int row0 = (b - 128) * 32;
        const float4* Xg = (const float4*)(x + (size_t)row0 * ATOMF);
        float4* Xl4 = (float4*)Xl;
        #pragma unroll
        for (int i = t; i < 32 * ATOMF / 4; i += 256) Xl4[i] = Xg[i];
        __syncthreads();
        int cg = t & 31, rg = t >> 5;
        int c0 = cg * 4;
        float acc[4][4];
        #pragma unroll
        for (int r = 0; r < 4; ++r)
            #pragma unroll
            for (int c = 0; c < 4; ++c) acc[r][c] = 0.f;
        for (int k = 0; k < ATOMF; k += 4) {
            float4 w0 = *(const float4*)(W0 + (size_t)(k + 0) * HID + c0);
            float4 w1 = *(const float4*)(W0 + (size_t)(k + 1) * HID + c0);
            float4 w2 = *(const float4*)(W0 + (size_t)(k + 2) * HID + c0);
            float4 w3 = *(const float4*)(W0 + (size_t)(k + 3) * HID + c0);
            #pragma unroll
            for (int r = 0; r < 4; ++r) {
                float4 xv = *(const float4*)(&Xl[(rg * 4 + r) * ATOMF + k]);
                acc[r][0] += xv.x * w0.x + xv.y * w1.x + xv.z * w2.x + xv.w * w3.x;
                acc[r][1] += xv.x * w0.y + xv.y * w1.y + xv.z * w2.y + xv.w * w3.y;
                acc[r][2] += xv.x * w0.z + xv.y * w1.z + xv.z * w2.z + xv.w * w3.z;
                acc[r][3] += xv.x * w0.w + xv.y * w1.w + xv.z * w2.w + xv.w * w3.w;
            }
        }
        float4 asv = *(const float4*)(a0s + c0);
        float4 adv = *(const float4*)(a0d + c0);
        #pragma unroll
        for (int r = 0; r < 4; ++r) {
            int row = row0 + rg * 4 + r;
            *(float4*)(g0 + (size_t)row * HID + c0) =
                make_float4(acc[r][0], acc[r][1], acc[r][2], acc[r][3]);
            float ps = acc[r][0] * asv.x + acc[r][1] * asv.y + acc[r][2] * asv.z + acc[r][3] * asv.w;
            float pd = acc[r][0] * adv.x + acc[r][1] * adv.y + acc[r][2] * adv.z + acc[r][3] * adv.w;
            #pragma unroll
            for (int o = 16; o; o >>= 1) {
                ps += __shfl_xor(ps, o);
                pd += __shfl_xor(pd, o);
            }
            if (cg == 0) { ssrc[row] = ps; sdst[row] = pd; }
        }
    }
}

// ================= K3/K4/K5: fused layer kernel (R8 verbatim + grid-modulo) =====
template<int DO_GEMM>
__global__ __launch_bounds__(256, 4) void k_layer(
    const float* __restrict__ g, const float* __restrict__ ssrc_in,
    const float* __restrict__ sdst_in,
    const int* __restrict__ ell, const int* __restrict__ deg,
    const float* __restrict__ Wr, const float* __restrict__ as_,
    const float* __restrict__ ad_,
    float* __restrict__ gout, float* __restrict__ ssrc_out,
    float* __restrict__ sdst_out) {
    __shared__ float wls[4][ELLW];
    __shared__ int jls[4][ELLW];
    __shared__ float xls[4][HID];
    int wid = threadIdx.x >> 6, l = threadIdx.x & 63;
    int row = (blockIdx.x & 2047) * 4 + wid;
    float* wl = wls[wid];
    int* jl = jls[wid];
    int d = deg[row];
    float si = ssrc_in[row];
    const int* er = ell + (size_t)row * ELLW;
    float m = -1e30f;
    for (int k = l; k < d; k += 64) {
        int j = er[k];
        float e = si + sdst_in[j];
        e = e > 0.f ? e : NEGSLOPE * e;
        jl[k] = j; wl[k] = e;
        m = fmaxf(m, e);
    }
    #pragma unroll
    for (int o = 32; o; o >>= 1) m = fmaxf(m, __shfl_xor(m, o));
    float s = 0.f;
    for (int k = l; k < d; k += 64) {
        float w = __expf(wl[k] - m);
        wl[k] = w;
        s += w;
    }
    #pragma unroll
    for (int o = 32; o; o >>= 1) s += __shfl_xor(s, o);
    float inv = 1.f / s;
    float a0 = 0.f, a1 = 0.f;
    const float* h2l = g + 2 * l;
    int k = 0;
    for (; k + 8 <= d; k += 8) {
        int j0 = jl[k],     j1 = jl[k + 1], j2 = jl[k + 2], j3 = jl[k + 3];
        int j4 = jl[k + 4], j5 = jl[k + 5], j6 = jl[k + 6], j7 = jl[k + 7];
        float w0 = wl[k],     w1 = wl[k + 1], w2 = wl[k + 2], w3 = wl[k + 3];
        float w4 = wl[k + 4], w5 = wl[k + 5], w6 = wl[k + 6], w7 = wl[k + 7];
        float2 v0 = *(const float2*)(h2l + (size_t)j0 * HID);
        float2 v1 = *(const float2*)(h2l + (size_t)j1 * HID);
        float2 v2 = *(const float2*)(h2l + (size_t)j2 * HID);
        float2 v3 = *(const float2*)(h2l + (size_t)j3 * HID);
        float2 v4 = *(const float2*)(h2l + (size_t)j4 * HID);
        float2 v5 = *(const float2*)(h2l + (size_t)j5 * HID);
        float2 v6 = *(const float2*)(h2l + (size_t)j6 * HID);
        float2 v7 = *(const float2*)(h2l + (size_t)j7 * HID);
        a0 += w0 * v0.x; a1 += w0 * v0.y;
        a0 += w1 * v1.x; a1 += w1 * v1.y;
        a0 += w2 * v2.x; a1 += w2 * v2.y;
        a0 += w3 * v3.x; a1 += w3 * v3.y;
        a0 += w4 * v4.x; a1 += w4 * v4.y;
        a0 += w5 * v5.x; a1 += w5 * v5.y;
        a0 += w6 * v6.x; a1 += w6 * v6.y;
        a0 += w7 * v7.x; a1 += w7 * v7.y;
    }
    for (; k < d; ++k) {
        int j = jl[k];
        float w = wl[k];
        float2 v = *(const float2*)(h2l + (size_t)j * HID);
        a0 += w * v.x; a1 += w * v.y;
    }
    a0 *= inv; a1 *= inv;
    if (DO_GEMM == 0) {
        *(float2*)(gout + (size_t)row * HID + 2 * l) = make_float2(a0, a1);
        return;
    }
    float* xl = xls[wid];
    xl[2 * l]     = fmaxf(a0, 0.f);
    xl[2 * l + 1] = fmaxf(a1, 0.f);
    float acc0 = 0.f, acc1 = 0.f;
    for (int kk = 0; kk < HID; kk += 4) {
        float4 xv = *(const float4*)(&xl[kk]);      // uniform addr: LDS broadcast
        float wa0 = Wr[(size_t)(kk + 0) * HID + l];
        float wb0 = Wr[(size_t)(kk + 0) * HID + l + 64];
        float wa1 = Wr[(size_t)(kk + 1) * HID + l];
        float wb1 = Wr[(size_t)(kk + 1) * HID + l + 64];
        float wa2 = Wr[(size_t)(kk + 2) * HID + l];
        float wb2 = Wr[(size_t)(kk + 2) * HID + l + 64];
        float wa3 = Wr[(size_t)(kk + 3) * HID + l];
        float wb3 = Wr[(size_t)(kk + 3) * HID + l + 64];
        acc0 += xv.x * wa0 + xv.y * wa1 + xv.z * wa2 + xv.w * wa3;
        acc1 += xv.x * wb0 + xv.y * wb1 + xv.z * wb2 + xv.w * wb3;
    }
    gout[(size_t)row * HID + l]      = acc0;
    gout[(size_t)row * HID + l + 64] = acc1;
    float ps = acc0 * as_[l] + acc1 * as_[l + 64];
    float pd = acc0 * ad_[l] + acc1 * ad_[l + 64];
    #pragma unroll
    for (int o = 32; o; o >>= 1) {
        ps += __shfl_xor(ps, o);
        pd += __shfl_xor(pd, o);
    }
    if (l == 0) { ssrc_out[row] = ps; sdst_out[row] = pd; }
}

// ================= K6: pool + fc (R8 verbatim) =================
__global__ __launch_bounds__(256) void k_poolfc(const float* __restrict__ h,
                                                const int* __restrict__ batch,
                                                const float* __restrict__ fcw,
                                                const float* __restrict__ fcb,
                                                float* __restrict__ out) {
    int wid = threadIdx.x >> 6, l = threadIdx.x & 63;
    int g = blockIdx.x * 4 + wid;
    int lo = 0, hi = NN;
    while (lo < hi) { int mid = (lo + hi) >> 1; if (batch[mid] < g) lo = mid + 1; else hi = mid; }
    int e0 = lo;
    hi = NN;
    while (lo < hi) { int mid = (lo + hi) >> 1; if (batch[mid] <= g) lo = mid + 1; else hi = mid; }
    int e1 = lo;
    float sum = 0.f;
    for (int r = e0; r < e1; ++r) {
        const float* hr = h + (size_t)r * HID;
        sum += hr[l] * fcw[l] + hr[l + 64] * fcw[l + 64];
    }
    #pragma unroll
    for (int o = 32; o; o >>= 1) sum += __shfl_xor(sum, o);
    if (l == 0) out[g] = sum / fmaxf((float)(e1 - e0), 1.f) + fcb[0];
}

extern "C" void kernel_launch(void* const* d_in, const int* in_sizes, int n_in,
                              void* d_out, int out_size, void* d_ws, size_t ws_size,
                              hipStream_t stream) {
    const float* x    = (const float*)d_in[0];
    const float* adj  = (const float*)d_in[1];
    const int*   batch= (const int*)  d_in[2];
    const float* W0   = (const float*)d_in[3];
    const float* a0s  = (const float*)d_in[4];
    const float* a0d  = (const float*)d_in[5];
    const float* W1   = (const float*)d_in[6];
    const float* a1s  = (const float*)d_in[7];
    const float* a1d  = (const float*)d_in[8];
    const float* W2   = (const float*)d_in[9];
    const float* a2s  = (const float*)d_in[10];
    const float* a2d  = (const float*)d_in[11];
    const float* fcw  = (const float*)d_in[12];
    const float* fcb  = (const float*)d_in[13];
    float* out = (float*)d_out;

    char* ws = (char*)d_ws;
    size_t off = 0;
    auto alloc = [&](size_t bytes) {
        char* p = ws + off;
        off = (off + bytes + 255) & ~255UL;
        return p;
    };
    int*   ell  = (int*)  alloc((size_t)NN * ELLW * 4);   // 6.3 MB
    int*   deg  = (int*)  alloc((size_t)NN * 4);
    float* hA   = (float*)alloc((size_t)NN * HID * 4);    // g0 / g2
    float* hB   = (float*)alloc((size_t)NN * HID * 4);    // g1 / h2
    float* sAs  = (float*)alloc((size_t)NN * 4);
    float* sAd  = (float*)alloc((size_t)NN * 4);
    float* sBs  = (float*)alloc((size_t)NN * 4);
    float* sBd  = (float*)alloc((size_t)NN * 4);
    float* Wr1  = (float*)alloc((size_t)HID * HID * 4);
    float* Wr2  = (float*)alloc((size_t)HID * HID * 4);
    // diagnostic scratch (ws_size ~1 GB per harness fills; we use < 30 MB)
    int*   ell2 = (int*)  alloc((size_t)NN * ELLW * 4);
    int*   deg2 = (int*)  alloc((size_t)NN * 4);
    float* hC   = (float*)alloc((size_t)NN * HID * 4);
    float* sCs  = (float*)alloc((size_t)NN * 4);
    float* sCd  = (float*)alloc((size_t)NN * 4);
    (void)ws_size; (void)in_sizes; (void)n_in; (void)out_size;

    // K1: adj -> ELL
    k_scan_ell<<<2048, 256, 0, stream>>>(adj, ell, deg);
    // K2: wreduce + gemm0/scores0
    k_front2<<<128 + 256, 256, 0, stream>>>(x, W0, a0s, a0d, W1, W2,
                                            Wr1, Wr2, hA, sAs, sAd);
    // K3: agg0 -> relu -> @Wr1 -> g1 + scores1
    k_layer<1><<<2048, 256, 0, stream>>>(hA, sAs, sAd, ell, deg, Wr1, a1s, a1d,
                                         hB, sBs, sBd);
    // DIAG-L: same layer kernel x12 into scratch (visible in top-5; /12 = true L)
    k_layer<1><<<12 * 2048, 256, 0, stream>>>(hA, sAs, sAd, ell, deg, Wr1, a1s, a1d,
                                              hC, sCs, sCd);
    // K4: agg1 -> relu -> @Wr2 -> g2 + scores2
    k_layer<1><<<2048, 256, 0, stream>>>(hB, sBs, sBd, ell, deg, Wr2, a2s, a2d,
                                         hA, sAs, sAd);
    // K5: agg2 -> h2
    k_layer<0><<<2048, 256, 0, stream>>>(hA, sAs, sAd, ell, deg, nullptr, nullptr,
                                         nullptr, hB, nullptr, nullptr);
    // K6: pool + fc
    k_poolfc<<<NG / 4, 256, 0, stream>>>(hB, batch, fcw, fcb, out);
    // DIAG-S: scan x3 into scratch (visible in top-5; /3 = true S)
    k_scan_ell<<<3 * 2048, 256, 0, stream>>>(adj, ell2, deg2);
}

// Round 10
// 171.052 us; speedup vs baseline: 4.4373x; 4.4373x over previous
//
#include <hip/hip_runtime.h>
#include <cstdint>
#include <cstddef>

#define NN 8192
#define ATOMF 64
#define HID 128
#define HEADS 8
#define NG 256
#define ELLW 192
#define NEGSLOPE 0.2f

typedef unsigned long long u64;

// ================= K1: adj -> ELL (lean, wave-per-row, LDS bitmask) — R9-measured ~23us ====
__global__ __launch_bounds__(256, 4) void k_scan_ell(const float* __restrict__ adj,
                                                     int* __restrict__ ell,
                                                     int* __restrict__ deg) {
    __shared__ u64 bml[4][128];
    int t = threadIdx.x, wid = t >> 6, l = t & 63;
    int row = blockIdx.x * 4 + wid;
    const float4* a4 = (const float4*)(adj + (size_t)row * NN);
    u64* bmr = bml[wid];
    #pragma unroll 8
    for (int s = 0; s < 32; ++s) {
        float4 v = a4[s * 64 + l];                  // coalesced 1 KB per wave-instr
        u64 b0 = __ballot(v.x > 0.f);
        u64 b1 = __ballot(v.y > 0.f);
        u64 b2 = __ballot(v.z > 0.f);
        u64 b3 = __ballot(v.w > 0.f);
        if (l < 4) bmr[s * 4 + l] = (l == 0) ? b0 : (l == 1) ? b1 : (l == 2) ? b2 : b3;
    }
    __syncthreads();
    // ---- expand from LDS (R7-proven encoding/order) ----
    u64 w0 = bmr[2 * l];
    u64 w1 = bmr[2 * l + 1];
    int c = __popcll(w0) + __popcll(w1);
    int incl = c;
    #pragma unroll
    for (int o = 1; o < 64; o <<= 1) {
        int u = __shfl_up(incl, o);
        if (l >= o) incl += u;
    }
    int pos = incl - c;
    int total = __shfl(incl, 63);
    if (l == 0) deg[row] = total < ELLW ? total : ELLW;
    int* er = ell + (size_t)row * ELLW;
    int gw0 = 2 * l, gw1 = 2 * l + 1;
    int base0 = (gw0 >> 2) * 256 + (gw0 & 3);
    int base1 = (gw1 >> 2) * 256 + (gw1 & 3);
    while (w0) {
        int bit = __builtin_ctzll(w0);
        w0 &= w0 - 1;
        if (pos < ELLW) er[pos++] = base0 + 4 * bit;
    }
    while (w1) {
        int bit = __builtin_ctzll(w1);
        w1 &= w1 - 1;
        if (pos < ELLW) er[pos++] = base1 + 4 * bit;
    }
}

// ================= K2: wreduce + gemm0/scores0 (R8 verbatim) ====
__global__ __launch_bounds__(256) void k_front2(
    const float* __restrict__ x,
    const float* __restrict__ W0, const float* __restrict__ a0s, const float* __restrict__ a0d,
    const float* __restrict__ W1, const float* __restrict__ W2,
    float* __restrict__ Wr1, float* __restrict__ Wr2,
    float* __restrict__ g0, float* __restrict__ ssrc, float* __restrict__ sdst) {
    int b = blockIdx.x, t = threadIdx.x;
    if (b < 128) {
        const float* W = (b < 64) ? W1 : W2;
        float* Wr = (b < 64) ? Wr1 : Wr2;
        int i = (b & 63) * 256 + t;
        int k = i >> 7, cc = i & 127;
        float s = 0.f;
        #pragma unroll
        for (int h = 0; h < HEADS; ++h) s += W[(size_t)(h * HID + k) * HID + cc];
        Wr[i] = s;
    } else {
        __shared__ float Xl[32 * ATOMF];
        int row0 = (b - 128) * 32;
        const float4* Xg = (const float4*)(x + (size_t)row0 * ATOMF);
        float4* Xl4 = (float4*)Xl;
        #pragma unroll
        for (int i = t; i < 32 * ATOMF / 4; i += 256) Xl4[i] = Xg[i];
        __syncthreads();
        int cg = t & 31, rg = t >> 5;
        int c0 = cg * 4;
        float acc[4][4];
        #pragma unroll
        for (int r = 0; r < 4; ++r)
            #pragma unroll
            for (int c = 0; c < 4; ++c) acc[r][c] = 0.f;
        for (int k = 0; k < ATOMF; k += 4) {
            float4 w0 = *(const float4*)(W0 + (size_t)(k + 0) * HID + c0);
            float4 w1 = *(const float4*)(W0 + (size_t)(k + 1) * HID + c0);
            float4 w2 = *(const float4*)(W0 + (size_t)(k + 2) * HID + c0);
            float4 w3 = *(const float4*)(W0 + (size_t)(k + 3) * HID + c0);
            #pragma unroll
            for (int r = 0; r < 4; ++r) {
                float4 xv = *(const float4*)(&Xl[(rg * 4 + r) * ATOMF + k]);
                acc[r][0] += xv.x * w0.x + xv.y * w1.x + xv.z * w2.x + xv.w * w3.x;
                acc[r][1] += xv.x * w0.y + xv.y * w1.y + xv.z * w2.y + xv.w * w3.y;
                acc[r][2] += xv.x * w0.z + xv.y * w1.z + xv.z * w2.z + xv.w * w3.z;
                acc[r][3] += xv.x * w0.w + xv.y * w1.w + xv.z * w2.w + xv.w * w3.w;
            }
        }
        float4 asv = *(const float4*)(a0s + c0);
        float4 adv = *(const float4*)(a0d + c0);
        #pragma unroll
        for (int r = 0; r < 4; ++r) {
            int row = row0 + rg * 4 + r;
            *(float4*)(g0 + (size_t)row * HID + c0) =
                make_float4(acc[r][0], acc[r][1], acc[r][2], acc[r][3]);
            float ps = acc[r][0] * asv.x + acc[r][1] * asv.y + acc[r][2] * asv.z + acc[r][3] * asv.w;
            float pd = acc[r][0] * adv.x + acc[r][1] * adv.y + acc[r][2] * adv.z + acc[r][3] * adv.w;
            #pragma unroll
            for (int o = 16; o; o >>= 1) {
                ps += __shfl_xor(ps, o);
                pd += __shfl_xor(pd, o);
            }
            if (cg == 0) { ssrc[row] = ps; sdst[row] = pd; }
        }
    }
}

// ================= K3/K4/K5: fused layer kernel — phase C restructured =====
// Phase C: 2 edges per wave-instr. Lane l owns dims (l&31)*4..+3 (float4);
// half = l>>5 picks the edge slot. jl holds PRESCALED j*HID. One shfl_xor(32)
// combines the two halves at the end.
template<int DO_GEMM>
__global__ __launch_bounds__(256, 4) void k_layer(
    const float* __restrict__ g, const float* __restrict__ ssrc_in,
    const float* __restrict__ sdst_in,
    const int* __restrict__ ell, const int* __restrict__ deg,
    const float* __restrict__ Wr, const float* __restrict__ as_,
    const float* __restrict__ ad_,
    float* __restrict__ gout, float* __restrict__ ssrc_out,
    float* __restrict__ sdst_out) {
    __shared__ float wls[4][ELLW + 2];
    __shared__ int jls[4][ELLW + 2];
    __shared__ float xls[4][HID];
    int wid = threadIdx.x >> 6, l = threadIdx.x & 63;
    int row = blockIdx.x * 4 + wid;
    float* wl = wls[wid];
    int* jl = jls[wid];
    int d = deg[row];
    float si = ssrc_in[row];
    const int* er = ell + (size_t)row * ELLW;
    // phase A: e = leakyrelu(s_i + s_j), running max; store prescaled index
    float m = -1e30f;
    for (int k = l; k < d; k += 64) {
        int j = er[k];
        float e = si + sdst_in[j];
        e = e > 0.f ? e : NEGSLOPE * e;
        jl[k] = j << 7;                              // j * HID
        wl[k] = e;
        m = fmaxf(m, e);
    }
    #pragma unroll
    for (int o = 32; o; o >>= 1) m = fmaxf(m, __shfl_xor(m, o));
    // phase B: softmax weights + denom
    float s = 0.f;
    for (int k = l; k < d; k += 64) {
        float w = __expf(wl[k] - m);
        wl[k] = w;
        s += w;
    }
    #pragma unroll
    for (int o = 32; o; o >>= 1) s += __shfl_xor(s, o);
    float inv = 1.f / s;
    if ((d & 1) && l == 0) { wl[d] = 0.f; jl[d] = 0; }   // pad to even (wave-private LDS, in-order)
    int dpad = d + (d & 1);
    // phase C: 2 edges per step, float4 per lane
    int half = l >> 5;
    int d0 = (l & 31) * 4;
    const float* hd = g + d0;
    float4 acc = make_float4(0.f, 0.f, 0.f, 0.f);
    int k = 0;
    for (; k + 8 <= dpad; k += 8) {                  // 4 pair-steps = 8 edges
        int j0 = jl[k + half],     j1 = jl[k + 2 + half];
        int j2 = jl[k + 4 + half], j3 = jl[k + 6 + half];
        float w0 = wl[k + half],     w1 = wl[k + 2 + half];
        float w2 = wl[k + 4 + half], w3 = wl[k + 6 + half];
        float4 v0 = *(const float4*)(hd + j0);
        float4 v1 = *(const float4*)(hd + j1);
        float4 v2 = *(const float4*)(hd + j2);
        float4 v3 = *(const float4*)(hd + j3);
        acc.x += w0 * v0.x; acc.y += w0 * v0.y; acc.z += w0 * v0.z; acc.w += w0 * v0.w;
        acc.x += w1 * v1.x; acc.y += w1 * v1.y; acc.z += w1 * v1.z; acc.w += w1 * v1.w;
        acc.x += w2 * v2.x; acc.y += w2 * v2.y; acc.z += w2 * v2.z; acc.w += w2 * v2.w;
        acc.x += w3 * v3.x; acc.y += w3 * v3.y; acc.z += w3 * v3.z; acc.w += w3 * v3.w;
    }
    for (; k < dpad; k += 2) {
        int j = jl[k + half];
        float w = wl[k + half];
        float4 v = *(const float4*)(hd + j);
        acc.x += w * v.x; acc.y += w * v.y; acc.z += w * v.z; acc.w += w * v.w;
    }
    acc.x += __shfl_xor(acc.x, 32);
    acc.y += __shfl_xor(acc.y, 32);
    acc.z += __shfl_xor(acc.z, 32);
    acc.w += __shfl_xor(acc.w, 32);
    acc.x *= inv; acc.y *= inv; acc.z *= inv; acc.w *= inv;
    if (DO_GEMM == 0) {
        if (l < 32)
            *(float4*)(gout + (size_t)row * HID + d0) = acc;
        return;
    }
    // stage relu(o_row) into wave-private LDS (lanes 0-31 cover all 128 dims)
    float* xl = xls[wid];
    if (l < 32) {
        float4 r;
        r.x = fmaxf(acc.x, 0.f); r.y = fmaxf(acc.y, 0.f);
        r.z = fmaxf(acc.z, 0.f); r.w = fmaxf(acc.w, 0.f);
        *(float4*)(xl + d0) = r;
    }
    // wave-private gemm: g' = relu(o) @ Wr ; lane owns cols l, l+64 (R8-proven)
    float acc0 = 0.f, acc1 = 0.f;
    for (int kk = 0; kk < HID; kk += 4) {
        float4 xv = *(const float4*)(&xl[kk]);      // uniform addr: LDS broadcast
        float wa0 = Wr[(size_t)(kk + 0) * HID + l];
        float wb0 = Wr[(size_t)(kk + 0) * HID + l + 64];
        float wa1 = Wr[(size_t)(kk + 1) * HID + l];
        float wb1 = Wr[(size_t)(kk + 1) * HID + l + 64];
        float wa2 = Wr[(size_t)(kk + 2) * HID + l];
        float wb2 = Wr[(size_t)(kk + 2) * HID + l + 64];
        float wa3 = Wr[(size_t)(kk + 3) * HID + l];
        float wb3 = Wr[(size_t)(kk + 3) * HID + l + 64];
        acc0 += xv.x * wa0 + xv.y * wa1 + xv.z * wa2 + xv.w * wa3;
        acc1 += xv.x * wb0 + xv.y * wb1 + xv.z * wb2 + xv.w * wb3;
    }
    gout[(size_t)row * HID + l]      = acc0;
    gout[(size_t)row * HID + l + 64] = acc1;
    float ps = acc0 * as_[l] + acc1 * as_[l + 64];
    float pd = acc0 * ad_[l] + acc1 * ad_[l + 64];
    #pragma unroll
    for (int o = 32; o; o >>= 1) {
        ps += __shfl_xor(ps, o);
        pd += __shfl_xor(pd, o);
    }
    if (l == 0) { ssrc_out[row] = ps; sdst_out[row] = pd; }
}

// ================= K6: pool + fc (R8 verbatim) =================
__global__ __launch_bounds__(256) void k_poolfc(const float* __restrict__ h,
                                                const int* __restrict__ batch,
                                                const float* __restrict__ fcw,
                                                const float* __restrict__ fcb,
                                                float* __restrict__ out) {
    int wid = threadIdx.x >> 6, l = threadIdx.x & 63;
    int g = blockIdx.x * 4 + wid;
    int lo = 0, hi = NN;
    while (lo < hi) { int mid = (lo + hi) >> 1; if (batch[mid] < g) lo = mid + 1; else hi = mid; }
    int e0 = lo;
    hi = NN;
    while (lo < hi) { int mid = (lo + hi) >> 1; if (batch[mid] <= g) lo = mid + 1; else hi = mid; }
    int e1 = lo;
    float sum = 0.f;
    for (int r = e0; r < e1; ++r) {
        const float* hr = h + (size_t)r * HID;
        sum += hr[l] * fcw[l] + hr[l + 64] * fcw[l + 64];
    }
    #pragma unroll
    for (int o = 32; o; o >>= 1) sum += __shfl_xor(sum, o);
    if (l == 0) out[g] = sum / fmaxf((float)(e1 - e0), 1.f) + fcb[0];
}

extern "C" void kernel_launch(void* const* d_in, const int* in_sizes, int n_in,
                              void* d_out, int out_size, void* d_ws, size_t ws_size,
                              hipStream_t stream) {
    const float* x    = (const float*)d_in[0];
    const float* adj  = (const float*)d_in[1];
    const int*   batch= (const int*)  d_in[2];
    const float* W0   = (const float*)d_in[3];
    const float* a0s  = (const float*)d_in[4];
    const float* a0d  = (const float*)d_in[5];
    const float* W1   = (const float*)d_in[6];
    const float* a1s  = (const float*)d_in[7];
    const float* a1d  = (const float*)d_in[8];
    const float* W2   = (const float*)d_in[9];
    const float* a2s  = (const float*)d_in[10];
    const float* a2d  = (const float*)d_in[11];
    const float* fcw  = (const float*)d_in[12];
    const float* fcb  = (const float*)d_in[13];
    float* out = (float*)d_out;

    char* ws = (char*)d_ws;
    size_t off = 0;
    auto alloc = [&](size_t bytes) {
        char* p = ws + off;
        off = (off + bytes + 255) & ~255UL;
        return p;
    };
    int*   ell  = (int*)  alloc((size_t)NN * ELLW * 4);   // 6.3 MB
    int*   deg  = (int*)  alloc((size_t)NN * 4);
    float* hA   = (float*)alloc((size_t)NN * HID * 4);    // g0 / g2
    float* hB   = (float*)alloc((size_t)NN * HID * 4);    // g1 / h2
    float* sAs  = (float*)alloc((size_t)NN * 4);
    float* sAd  = (float*)alloc((size_t)NN * 4);
    float* sBs  = (float*)alloc((size_t)NN * 4);
    float* sBd  = (float*)alloc((size_t)NN * 4);
    float* Wr1  = (float*)alloc((size_t)HID * HID * 4);
    float* Wr2  = (float*)alloc((size_t)HID * HID * 4);
    (void)ws_size; (void)in_sizes; (void)n_in; (void)out_size;

    // K1: adj -> ELL
    k_scan_ell<<<NN / 4, 256, 0, stream>>>(adj, ell, deg);
    // K2: wreduce + gemm0/scores0
    k_front2<<<128 + 256, 256, 0, stream>>>(x, W0, a0s, a0d, W1, W2,
                                            Wr1, Wr2, hA, sAs, sAd);
    // K3: agg0 -> relu -> @Wr1 -> g1 + scores1
    k_layer<1><<<NN / 4, 256, 0, stream>>>(hA, sAs, sAd, ell, deg, Wr1, a1s, a1d,
                                           hB, sBs, sBd);
    // K4: agg1 -> relu -> @Wr2 -> g2 + scores2
    k_layer<1><<<NN / 4, 256, 0, stream>>>(hB, sBs, sBd, ell, deg, Wr2, a2s, a2d,
                                           hA, sAs, sAd);
    // K5: agg2 -> h2
    k_layer<0><<<NN / 4, 256, 0, stream>>>(hA, sAs, sAd, ell, deg, nullptr, nullptr,
                                           nullptr, hB, nullptr, nullptr);
    // K6: pool + fc
    k_poolfc<<<NG / 4, 256, 0, stream>>>(hB, batch, fcw, fcb, out);
}